// Round 6
// baseline (496.834 us; speedup 1.0000x reference)
//
#include <hip/hip_runtime.h>
#include <hip/hip_bf16.h>

// N=16384 queries, C=1024 classes, D=4096.
// sims = l2norm(hvs) @ l2norm(am)^T ; preds = argmax ; eta = (sims[:,1]-sims[:,0])/4 + 0.5
// R6: pass1 GEMM moves to mfma_32x32x16 (half the LDS bytes per FLOP);
// pass2 recheck restructured to 128-row blocks with the proven dbuf+counted-
// vmcnt skeleton and gathered A rows (4x less B traffic, latency hidden).

#define NQ 16384
#define NC 1024
#define DK 4096
#define TAU 4e-4f

typedef __attribute__((ext_vector_type(8))) short short8;
typedef __attribute__((ext_vector_type(4))) float f32x4;
typedef __attribute__((ext_vector_type(16))) float f32x16;
typedef unsigned short ushort_t;

__device__ __forceinline__ unsigned short bf16_rne(float x) {
    unsigned int u = __float_as_uint(x);
    u += 0x7FFFu + ((u >> 16) & 1u);
    return (unsigned short)(u >> 16);
}
__device__ __forceinline__ float bf16_f32(unsigned short h) {
    return __uint_as_float(((unsigned int)h) << 16);
}

#define GLDS(g, l)                                                                       \
    __builtin_amdgcn_global_load_lds((const __attribute__((address_space(1))) void*)(g), \
                                     (__attribute__((address_space(3))) void*)(l), 16, 0, 0)

// ---------------- fused row-norm + normalize + bf16 hi/lo split ----------------
__global__ void __launch_bounds__(256) norm_split_kernel(const float* __restrict__ x,
                                                         ushort_t* __restrict__ hi,
                                                         ushort_t* __restrict__ lo) {
    const int row = blockIdx.x;
    const int tid = threadIdx.x;
    const float4* x4 = (const float4*)(x + (size_t)row * DK);

    float4 v[4];
    float ss = 0.f;
#pragma unroll
    for (int i = 0; i < 4; ++i) {
        v[i] = x4[tid * 4 + i];
        ss += v[i].x * v[i].x + v[i].y * v[i].y + v[i].z * v[i].z + v[i].w * v[i].w;
    }
#pragma unroll
    for (int off = 32; off; off >>= 1) ss += __shfl_xor(ss, off, 64);
    __shared__ float wsum[4];
    const int lane = tid & 63, w = tid >> 6;
    if (lane == 0) wsum[w] = ss;
    __syncthreads();
    const float tot = wsum[0] + wsum[1] + wsum[2] + wsum[3];
    const float r = 1.0f / fmaxf(sqrtf(tot), 1e-8f);

    ushort_t hbuf[16], lbuf[16];
#pragma unroll
    for (int i = 0; i < 4; ++i) {
        const float xs[4] = {v[i].x * r, v[i].y * r, v[i].z * r, v[i].w * r};
#pragma unroll
        for (int j = 0; j < 4; ++j) {
            const unsigned short h = bf16_rne(xs[j]);
            hbuf[i * 4 + j] = h;
            lbuf[i * 4 + j] = bf16_rne(xs[j] - bf16_f32(h));
        }
    }
    ushort_t* hp = hi + (size_t)row * DK + tid * 16;
    ushort_t* lp = lo + (size_t)row * DK + tid * 16;
    *(short8*)hp = *(short8*)hbuf;
    *(short8*)(hp + 8) = *(short8*)(hbuf + 8);
    *(short8*)lp = *(short8*)lbuf;
    *(short8*)(lp + 8) = *(short8*)(lbuf + 8);
}

// ---------------- pass 1: 1-term bf16 GEMM, 32x32x16, BK=64, fused top-2 ----------------
// 256x256 tile, 8 waves (2Mx4N), per-wave 128x64 as 4x2 tiles of 32x32.
// dbuf LDS 128 KB, issue-early staging + counted vmcnt(8), 8-slot XOR swizzle.
__global__ void __launch_bounds__(512, 2) gemm1_kernel(const ushort_t* __restrict__ Ah,
                                                       const ushort_t* __restrict__ Bh,
                                                       float4* __restrict__ cand,
                                                       float* __restrict__ s01) {
    __shared__ __align__(16) ushort_t lA[2][256 * 64];  // 64 KB
    __shared__ __align__(16) ushort_t lB[2][256 * 64];  // 64 KB

    const int tid = threadIdx.x;
    const int lane = tid & 63;
    const int w = tid >> 6;   // 0..7
    const int wm = w >> 2;    // 0..1
    const int wn = w & 3;     // 0..3

    // bijective XCD swizzle: 4 bx-blocks sharing a by-panel land on one XCD
    const int id = blockIdx.x;             // 0..255
    const int xcd = id & 7;
    const int slot = id >> 3;              // 0..31
    const int by = xcd * 8 + (slot >> 2);  // 0..63
    const int bx = slot & 3;               // 0..3

    // staging: per operand tile = 256 rows x 8 slots(16B) = 2048 chunks; 4/thread
    int sq[4];
    size_t offA[4], offB[4];
#pragma unroll
    for (int i = 0; i < 4; ++i) {
        const int q = tid + i * 512;
        sq[i] = q;
        const int srow = q >> 3;
        const int gs = (q & 7) ^ (srow & 7);
        offA[i] = (size_t)(by * 256 + srow) * DK + gs * 8;
        offB[i] = (size_t)(bx * 256 + srow) * DK + gs * 8;
    }

    f32x16 acc[4][2];
#pragma unroll
    for (int m = 0; m < 4; ++m)
#pragma unroll
        for (int n = 0; n < 2; ++n)
#pragma unroll
            for (int j = 0; j < 16; ++j) acc[m][n][j] = 0.f;

    const int c5 = lane & 31;  // row-in-32 (A) / col-in-32 (B)
    const int hf = lane >> 5;  // k-octet half

    // frag LDS offsets (shorts): desired global octet o of row r lives at slot o^(r&7)
    int aoff[4][4], boff[2][4];
#pragma unroll
    for (int m = 0; m < 4; ++m) {
        const int row = wm * 128 + m * 32 + c5;
#pragma unroll
        for (int ks = 0; ks < 4; ++ks)
            aoff[m][ks] = row * 64 + ((ks * 2 + hf) ^ (row & 7)) * 8;
    }
#pragma unroll
    for (int n = 0; n < 2; ++n) {
        const int col = wn * 64 + n * 32 + c5;
#pragma unroll
        for (int ks = 0; ks < 4; ++ks)
            boff[n][ks] = col * 64 + ((ks * 2 + hf) ^ (col & 7)) * 8;
    }

    auto stage = [&](int buf, int kt) {
        const size_t ko = (size_t)kt * 64;
#pragma unroll
        for (int i = 0; i < 4; ++i) {
            GLDS(Ah + offA[i] + ko, &lA[buf][sq[i] * 8]);
            GLDS(Bh + offB[i] + ko, &lB[buf][sq[i] * 8]);
        }
    };

    stage(0, 0);
    const int nK = DK / 64;  // 64
    for (int kt = 0; kt < nK; ++kt) {
        const int cur = kt & 1;
        if (kt + 1 < nK) {
            stage(cur ^ 1, kt + 1);                           // 8 new loads in flight
            asm volatile("s_waitcnt vmcnt(8)" ::: "memory");  // cur's 8 done
        } else {
            asm volatile("s_waitcnt vmcnt(0)" ::: "memory");
        }
        __builtin_amdgcn_s_barrier();

#pragma unroll
        for (int ks = 0; ks < 4; ++ks) {
            const short8 b0 = *(const short8*)&lB[cur][boff[0][ks]];
            const short8 b1 = *(const short8*)&lB[cur][boff[1][ks]];
#pragma unroll
            for (int m = 0; m < 4; ++m) {
                const short8 a = *(const short8*)&lA[cur][aoff[m][ks]];
                acc[m][0] = __builtin_amdgcn_mfma_f32_32x32x16_bf16(a, b0, acc[m][0], 0, 0, 0);
                acc[m][1] = __builtin_amdgcn_mfma_f32_32x32x16_bf16(a, b1, acc[m][1], 0, 0, 0);
            }
        }
        __builtin_amdgcn_s_barrier();
    }

    // epilogue: C/D layout col=lane&31, row=(reg&3)+8*(reg>>2)+4*(lane>>5) [m74/m101]
    // per (m,reg): top-2 over the wave's 64 cols (2 n-tiles x 32 lanes per half)
    const int rowb = by * 256 + wm * 128;
#pragma unroll
    for (int m = 0; m < 4; ++m) {
#pragma unroll
        for (int reg = 0; reg < 16; ++reg) {
            const float va = acc[m][0][reg];
            const float vb = acc[m][1][reg];
            float v1, v2;
            int i1;
            const int colb = bx * 256 + wn * 64 + c5;
            if (va >= vb) { v1 = va; i1 = colb; v2 = vb; }
            else          { v1 = vb; i1 = colb + 32; v2 = va; }
#pragma unroll
            for (int off = 1; off < 32; off <<= 1) {
                const float o1 = __shfl_xor(v1, off, 64);
                const int oi = __shfl_xor(i1, off, 64);
                const float o2 = __shfl_xor(v2, off, 64);
                if (o1 > v1 || (o1 == v1 && oi < i1)) { v2 = fmaxf(v1, o2); v1 = o1; i1 = oi; }
                else { v2 = fmaxf(v2, o1); }
            }
            const int row = rowb + m * 32 + (reg & 3) + 8 * (reg >> 2) + 4 * hf;
            if (c5 == 0)
                cand[(size_t)row * 16 + bx * 4 + wn] = make_float4(v1, (float)i1, v2, 0.f);
            if (bx == 0 && wn == 0 && c5 < 2) s01[row * 2 + c5] = acc[m][0][reg];
        }
    }
}

// ---------------- finalize pass 1: merge strips, flag close rows ----------------
__global__ void __launch_bounds__(256) finalizeA_kernel(const float4* __restrict__ cand,
                                                        const float* __restrict__ s01,
                                                        float* __restrict__ out,
                                                        int* __restrict__ wl,
                                                        int* __restrict__ wc) {
    const int row = blockIdx.x * 256 + threadIdx.x;
    const float4* c = cand + (size_t)row * 16;
    float4 c0 = c[0];
    float M = c0.x, iM = c0.y, M2 = c0.z;
#pragma unroll
    for (int k = 1; k < 16; ++k) {
        const float4 ck = c[k];
        if (ck.x > M) { M2 = fmaxf(M, ck.z); M = ck.x; iM = ck.y; }
        else { M2 = fmaxf(M2, ck.x); }
    }
    out[row] = iM;
    out[NQ + row] = (s01[row * 2 + 1] - s01[row * 2 + 0]) * 0.25f + 0.5f;
    if (M - M2 < TAU) {
        const int p = atomicAdd(wc, 1);
        wl[p] = row;
    }
}

// ---------------- pass 2: 3-term recheck, 128x256 tile, gathered A rows ----------------
// 8 waves (2Mx4N, each 64x64), dbuf LDS 96 KB, issue-early + counted vmcnt(6).
// Arithmetic per-acc identical to the proven R3 3-term path (absmax 0).
__global__ void __launch_bounds__(512, 2) gemm2_kernel(const ushort_t* __restrict__ Ah,
                                                       const ushort_t* __restrict__ Al,
                                                       const ushort_t* __restrict__ Bh,
                                                       const ushort_t* __restrict__ Bl,
                                                       const int* __restrict__ wl,
                                                       const int* __restrict__ wc,
                                                       float2* __restrict__ cand2) {
    const int cnt = *wc;
    const int by = blockIdx.y;  // slot block (128 rows)
    const int bx = blockIdx.x;  // 256-col block
    if (by * 128 >= cnt) return;

    __shared__ __align__(16) ushort_t lA[2][2][128 * 32];  // [buf][hi/lo] 32 KB
    __shared__ __align__(16) ushort_t lB[2][2][256 * 32];  // 64 KB

    const int tid = threadIdx.x;
    const int lane = tid & 63;
    const int w = tid >> 6;  // 0..7
    const int wm = w >> 2;   // 0..1
    const int wn = w & 3;    // 0..3
    const int r0 = lane & 15;
    const int rg = lane >> 4;

    // A staging: 128 rows x 4 slots = 512 chunks; 1/thread (each for hi and lo)
    const int rowA = tid >> 2;
    const int gsA = (tid & 3) ^ ((rowA >> 1) & 3);
    const int arow = wl[min(by * 128 + rowA, cnt - 1)];
    const size_t offA = (size_t)arow * DK + gsA * 8;
    // B staging: 256 rows x 4 slots = 1024 chunks; 2/thread
    const int qb0 = tid, qb1 = tid + 512;
    const int rowB0 = qb0 >> 2, rowB1 = qb1 >> 2;
    const int gsB0 = (qb0 & 3) ^ ((rowB0 >> 1) & 3);
    const int gsB1 = (qb1 & 3) ^ ((rowB1 >> 1) & 3);
    const size_t offB0 = (size_t)(bx * 256 + rowB0) * DK + gsB0 * 8;
    const size_t offB1 = (size_t)(bx * 256 + rowB1) * DK + gsB1 * 8;

    f32x4 acc[4][4];
#pragma unroll
    for (int m = 0; m < 4; ++m)
#pragma unroll
        for (int n = 0; n < 4; ++n) acc[m][n] = (f32x4){0.f, 0.f, 0.f, 0.f};

    int aoff[4], boff[4];
#pragma unroll
    for (int m = 0; m < 4; ++m) {
        const int row = wm * 64 + m * 16 + r0;
        aoff[m] = row * 32 + (rg ^ ((row >> 1) & 3)) * 8;
    }
#pragma unroll
    for (int n = 0; n < 4; ++n) {
        const int col = wn * 64 + n * 16 + r0;
        boff[n] = col * 32 + (rg ^ ((col >> 1) & 3)) * 8;
    }

    auto stage = [&](int buf, int kt) {
        const size_t ko = (size_t)kt * 32;
        GLDS(Ah + offA + ko, &lA[buf][0][tid * 8]);
        GLDS(Al + offA + ko, &lA[buf][1][tid * 8]);
        GLDS(Bh + offB0 + ko, &lB[buf][0][qb0 * 8]);
        GLDS(Bl + offB0 + ko, &lB[buf][1][qb0 * 8]);
        GLDS(Bh + offB1 + ko, &lB[buf][0][qb1 * 8]);
        GLDS(Bl + offB1 + ko, &lB[buf][1][qb1 * 8]);
    };

    stage(0, 0);
    const int nK = DK / 32;  // 128
    for (int kt = 0; kt < nK; ++kt) {
        const int cur = kt & 1;
        if (kt + 1 < nK) {
            stage(cur ^ 1, kt + 1);                           // 6 new loads in flight
            asm volatile("s_waitcnt vmcnt(6)" ::: "memory");  // cur's 6 done
        } else {
            asm volatile("s_waitcnt vmcnt(0)" ::: "memory");
        }
        __builtin_amdgcn_s_barrier();

        short8 bh[4], bl[4];
#pragma unroll
        for (int n = 0; n < 4; ++n) {
            bh[n] = *(const short8*)&lB[cur][0][boff[n]];
            bl[n] = *(const short8*)&lB[cur][1][boff[n]];
        }
#pragma unroll
        for (int m = 0; m < 4; ++m) {
            const short8 ah = *(const short8*)&lA[cur][0][aoff[m]];
            const short8 al = *(const short8*)&lA[cur][1][aoff[m]];
#pragma unroll
            for (int n = 0; n < 4; ++n) {
                acc[m][n] = __builtin_amdgcn_mfma_f32_16x16x32_bf16(ah, bh[n], acc[m][n], 0, 0, 0);
                acc[m][n] = __builtin_amdgcn_mfma_f32_16x16x32_bf16(ah, bl[n], acc[m][n], 0, 0, 0);
                acc[m][n] = __builtin_amdgcn_mfma_f32_16x16x32_bf16(al, bh[n], acc[m][n], 0, 0, 0);
            }
        }
        __builtin_amdgcn_s_barrier();
    }

    // epilogue: argmax over wave's 64 cols -> cand2[slot][bx*4+wn]
#pragma unroll
    for (int m = 0; m < 4; ++m) {
#pragma unroll
        for (int j = 0; j < 4; ++j) {
            float best = acc[m][0][j];
            int bidx = bx * 256 + wn * 64 + r0;
#pragma unroll
            for (int n = 1; n < 4; ++n) {
                const float v = acc[m][n][j];
                const int c = bx * 256 + wn * 64 + n * 16 + r0;
                if (v > best) { best = v; bidx = c; }
            }
#pragma unroll
            for (int off = 1; off < 16; off <<= 1) {
                const float ov = __shfl_xor(best, off, 64);
                const int oi = __shfl_xor(bidx, off, 64);
                if (ov > best || (ov == best && oi < bidx)) { best = ov; bidx = oi; }
            }
            const int slotg = by * 128 + wm * 64 + m * 16 + rg * 4 + j;
            if (r0 == 0 && slotg < cnt)
                cand2[(size_t)slotg * 16 + bx * 4 + wn] = make_float2(best, (float)bidx);
        }
    }
}

// ---------------- finalize pass 2 ----------------
__global__ void __launch_bounds__(256) finalizeB_kernel(const float2* __restrict__ cand2,
                                                        const int* __restrict__ wl,
                                                        const int* __restrict__ wc,
                                                        float* __restrict__ out) {
    const int slot = blockIdx.x * 256 + threadIdx.x;
    const int cnt = *wc;
    if (slot >= cnt) return;
    const int row = wl[slot];
    const float2* c = cand2 + (size_t)slot * 16;
    float best = c[0].x;
    float bi = c[0].y;
#pragma unroll
    for (int k = 1; k < 16; ++k) {
        const float2 p = c[k];
        if (p.x > best) { best = p.x; bi = p.y; }  // ascending cols: strict > keeps first
    }
    out[row] = bi;
}

extern "C" void kernel_launch(void* const* d_in, const int* in_sizes, int n_in,
                              void* d_out, int out_size, void* d_ws, size_t ws_size,
                              hipStream_t stream) {
    const float* hvs = (const float*)d_in[0];  // [16384,4096] f32
    const float* am  = (const float*)d_in[1];  // [1024,4096] f32
    float* out = (float*)d_out;                // [preds | eta]

    ushort_t* Bh = (ushort_t*)d_ws;                    // 8 MB
    ushort_t* Bl = Bh + (size_t)NC * DK;               // 8 MB
    ushort_t* Ah = Bl + (size_t)NC * DK;               // 128 MB
    ushort_t* Al = Ah + (size_t)NQ * DK;               // 128 MB
    float4* cand = (float4*)(Al + (size_t)NQ * DK);    // 4 MB
    float* s01 = (float*)(cand + (size_t)NQ * 16);     // 128 KB
    float2* cand2 = (float2*)(s01 + (size_t)NQ * 2);   // 2 MB
    int* wl = (int*)(cand2 + (size_t)NQ * 16);         // 64 KB
    int* wc = wl + NQ;                                 // 4 B

    hipMemsetAsync(wc, 0, sizeof(int), stream);
    norm_split_kernel<<<NC, 256, 0, stream>>>(am, Bh, Bl);
    norm_split_kernel<<<NQ, 256, 0, stream>>>(hvs, Ah, Al);
    gemm1_kernel<<<256, 512, 0, stream>>>(Ah, Bh, cand, s01);
    finalizeA_kernel<<<NQ / 256, 256, 0, stream>>>(cand, s01, out, wl, wc);
    gemm2_kernel<<<dim3(4, NQ / 128), 512, 0, stream>>>(Ah, Al, Bh, Bl, wl, wc, cand2);
    finalizeB_kernel<<<NQ / 256, 256, 0, stream>>>(cand2, wl, wc, out);
}

// Round 7
// 476.253 us; speedup vs baseline: 1.0432x; 1.0432x over previous
//
#include <hip/hip_runtime.h>
#include <hip/hip_bf16.h>

// N=16384 queries, C=1024 classes, D=4096.
// sims = l2norm(hvs) @ l2norm(am)^T ; preds = argmax ; eta = (sims[:,1]-sims[:,0])/4 + 0.5
// R7: gemm1 = m201-style half-tile ring: 4 LDS half-buffers (K=32 each),
// 3 halves prefetched, counted vmcnt(8), 2 phases/half with setprio MFMA
// clusters. R3-proven (row>>1)&3 XOR swizzle. Pass 2 recheck unchanged (R6).

#define NQ 16384
#define NC 1024
#define DK 4096
#define TAU 4e-4f

typedef __attribute__((ext_vector_type(8))) short short8;
typedef __attribute__((ext_vector_type(4))) float f32x4;
typedef unsigned short ushort_t;

__device__ __forceinline__ unsigned short bf16_rne(float x) {
    unsigned int u = __float_as_uint(x);
    u += 0x7FFFu + ((u >> 16) & 1u);
    return (unsigned short)(u >> 16);
}
__device__ __forceinline__ float bf16_f32(unsigned short h) {
    return __uint_as_float(((unsigned int)h) << 16);
}

#define GLDS(g, l)                                                                       \
    __builtin_amdgcn_global_load_lds((const __attribute__((address_space(1))) void*)(g), \
                                     (__attribute__((address_space(3))) void*)(l), 16, 0, 0)

// ---------------- fused row-norm + normalize + bf16 hi/lo split ----------------
__global__ void __launch_bounds__(256) norm_split_kernel(const float* __restrict__ x,
                                                         ushort_t* __restrict__ hi,
                                                         ushort_t* __restrict__ lo) {
    const int row = blockIdx.x;
    const int tid = threadIdx.x;
    const float4* x4 = (const float4*)(x + (size_t)row * DK);

    float4 v[4];
    float ss = 0.f;
#pragma unroll
    for (int i = 0; i < 4; ++i) {
        v[i] = x4[tid * 4 + i];
        ss += v[i].x * v[i].x + v[i].y * v[i].y + v[i].z * v[i].z + v[i].w * v[i].w;
    }
#pragma unroll
    for (int off = 32; off; off >>= 1) ss += __shfl_xor(ss, off, 64);
    __shared__ float wsum[4];
    const int lane = tid & 63, w = tid >> 6;
    if (lane == 0) wsum[w] = ss;
    __syncthreads();
    const float tot = wsum[0] + wsum[1] + wsum[2] + wsum[3];
    const float r = 1.0f / fmaxf(sqrtf(tot), 1e-8f);

    ushort_t hbuf[16], lbuf[16];
#pragma unroll
    for (int i = 0; i < 4; ++i) {
        const float xs[4] = {v[i].x * r, v[i].y * r, v[i].z * r, v[i].w * r};
#pragma unroll
        for (int j = 0; j < 4; ++j) {
            const unsigned short h = bf16_rne(xs[j]);
            hbuf[i * 4 + j] = h;
            lbuf[i * 4 + j] = bf16_rne(xs[j] - bf16_f32(h));
        }
    }
    ushort_t* hp = hi + (size_t)row * DK + tid * 16;
    ushort_t* lp = lo + (size_t)row * DK + tid * 16;
    *(short8*)hp = *(short8*)hbuf;
    *(short8*)(hp + 8) = *(short8*)(hbuf + 8);
    *(short8*)lp = *(short8*)lbuf;
    *(short8*)(lp + 8) = *(short8*)(lbuf + 8);
}

// ---------------- pass 1: 1-term bf16 GEMM, half-tile ring, fused top-2 ----------------
// 256x256 tile, 8 waves (2Mx4N, each 128x64), 16x16x32 MFMA.
// 4 half-buffers (256x32 each) per operand = 128 KB; 3 halves in flight;
// per half: P0{4b+4a reads, 2 GLDS, bar, lgkm0, prio, 16 MFMA, bar},
//           P1{4a reads, 2 GLDS, bar, lgkm0, prio, 16 MFMA, vmcnt(8), bar}.
__global__ void __launch_bounds__(512, 2) gemm1_kernel(const ushort_t* __restrict__ Ah,
                                                       const ushort_t* __restrict__ Bh,
                                                       float4* __restrict__ cand,
                                                       float* __restrict__ s01) {
    __shared__ __align__(16) ushort_t lA[4][256 * 32];  // 64 KB
    __shared__ __align__(16) ushort_t lB[4][256 * 32];  // 64 KB

    const int tid = threadIdx.x;
    const int lane = tid & 63;
    const int w = tid >> 6;   // 0..7
    const int wm = w >> 2;    // 0..1
    const int wn = w & 3;     // 0..3

    // bijective XCD swizzle: 4 bx-blocks sharing a by-panel land on one XCD
    const int id = blockIdx.x;             // 0..255
    const int xcd = id & 7;
    const int slot = id >> 3;              // 0..31
    const int by = xcd * 8 + (slot >> 2);  // 0..63
    const int bx = slot & 3;               // 0..3

    // staging: per operand half-tile = 256 rows x 4 slots(16B) = 1024 chunks; 2/thread
    int sq[2];
    size_t offA[2], offB[2];
#pragma unroll
    for (int i = 0; i < 2; ++i) {
        const int q = tid + i * 512;
        sq[i] = q;
        const int row = q >> 2;
        const int gs = (q & 3) ^ ((row >> 1) & 3);  // R3-proven swizzle
        offA[i] = (size_t)(by * 256 + row) * DK + gs * 8;
        offB[i] = (size_t)(bx * 256 + row) * DK + gs * 8;
    }

    f32x4 acc[8][4];
#pragma unroll
    for (int m = 0; m < 8; ++m)
#pragma unroll
        for (int n = 0; n < 4; ++n) acc[m][n] = (f32x4){0.f, 0.f, 0.f, 0.f};

    const int r0 = lane & 15;
    const int rg = lane >> 4;  // k-octet 0..3 within the half

    int aoff[8], boff[4];
#pragma unroll
    for (int m = 0; m < 8; ++m) {
        const int row = wm * 128 + m * 16 + r0;
        aoff[m] = row * 32 + (rg ^ ((row >> 1) & 3)) * 8;
    }
#pragma unroll
    for (int n = 0; n < 4; ++n) {
        const int col = wn * 64 + n * 16 + r0;
        boff[n] = col * 32 + (rg ^ ((col >> 1) & 3)) * 8;
    }

    auto stage_half = [&](int H, int i) {  // issue chunk i of half H (2 GLDS)
        const int buf = H & 3;
        const size_t ko = (size_t)H * 32;
        GLDS(Ah + offA[i] + ko, &lA[buf][sq[i] * 8]);
        GLDS(Bh + offB[i] + ko, &lB[buf][sq[i] * 8]);
    };

    auto half_body = [&](int H, bool st, int gate) {
        const int buf = H & 3;
        const ushort_t* __restrict__ pA = &lA[buf][0];
        const ushort_t* __restrict__ pB = &lB[buf][0];
        // ---- P0 ----
        short8 b0 = *(const short8*)&pB[boff[0]];
        short8 b1 = *(const short8*)&pB[boff[1]];
        short8 b2 = *(const short8*)&pB[boff[2]];
        short8 b3 = *(const short8*)&pB[boff[3]];
        short8 a0 = *(const short8*)&pA[aoff[0]];
        short8 a1 = *(const short8*)&pA[aoff[1]];
        short8 a2 = *(const short8*)&pA[aoff[2]];
        short8 a3 = *(const short8*)&pA[aoff[3]];
        if (st) stage_half(H + 3, 0);
        __builtin_amdgcn_s_barrier();
        asm volatile("s_waitcnt lgkmcnt(0)" ::: "memory");
        __builtin_amdgcn_s_setprio(1);
        acc[0][0] = __builtin_amdgcn_mfma_f32_16x16x32_bf16(a0, b0, acc[0][0], 0, 0, 0);
        acc[0][1] = __builtin_amdgcn_mfma_f32_16x16x32_bf16(a0, b1, acc[0][1], 0, 0, 0);
        acc[0][2] = __builtin_amdgcn_mfma_f32_16x16x32_bf16(a0, b2, acc[0][2], 0, 0, 0);
        acc[0][3] = __builtin_amdgcn_mfma_f32_16x16x32_bf16(a0, b3, acc[0][3], 0, 0, 0);
        acc[1][0] = __builtin_amdgcn_mfma_f32_16x16x32_bf16(a1, b0, acc[1][0], 0, 0, 0);
        acc[1][1] = __builtin_amdgcn_mfma_f32_16x16x32_bf16(a1, b1, acc[1][1], 0, 0, 0);
        acc[1][2] = __builtin_amdgcn_mfma_f32_16x16x32_bf16(a1, b2, acc[1][2], 0, 0, 0);
        acc[1][3] = __builtin_amdgcn_mfma_f32_16x16x32_bf16(a1, b3, acc[1][3], 0, 0, 0);
        acc[2][0] = __builtin_amdgcn_mfma_f32_16x16x32_bf16(a2, b0, acc[2][0], 0, 0, 0);
        acc[2][1] = __builtin_amdgcn_mfma_f32_16x16x32_bf16(a2, b1, acc[2][1], 0, 0, 0);
        acc[2][2] = __builtin_amdgcn_mfma_f32_16x16x32_bf16(a2, b2, acc[2][2], 0, 0, 0);
        acc[2][3] = __builtin_amdgcn_mfma_f32_16x16x32_bf16(a2, b3, acc[2][3], 0, 0, 0);
        acc[3][0] = __builtin_amdgcn_mfma_f32_16x16x32_bf16(a3, b0, acc[3][0], 0, 0, 0);
        acc[3][1] = __builtin_amdgcn_mfma_f32_16x16x32_bf16(a3, b1, acc[3][1], 0, 0, 0);
        acc[3][2] = __builtin_amdgcn_mfma_f32_16x16x32_bf16(a3, b2, acc[3][2], 0, 0, 0);
        acc[3][3] = __builtin_amdgcn_mfma_f32_16x16x32_bf16(a3, b3, acc[3][3], 0, 0, 0);
        __builtin_amdgcn_s_setprio(0);
        __builtin_amdgcn_s_barrier();
        // ---- P1 ----
        short8 a4 = *(const short8*)&pA[aoff[4]];
        short8 a5 = *(const short8*)&pA[aoff[5]];
        short8 a6 = *(const short8*)&pA[aoff[6]];
        short8 a7 = *(const short8*)&pA[aoff[7]];
        if (st) stage_half(H + 3, 1);
        __builtin_amdgcn_s_barrier();
        asm volatile("s_waitcnt lgkmcnt(0)" ::: "memory");
        __builtin_amdgcn_s_setprio(1);
        acc[4][0] = __builtin_amdgcn_mfma_f32_16x16x32_bf16(a4, b0, acc[4][0], 0, 0, 0);
        acc[4][1] = __builtin_amdgcn_mfma_f32_16x16x32_bf16(a4, b1, acc[4][1], 0, 0, 0);
        acc[4][2] = __builtin_amdgcn_mfma_f32_16x16x32_bf16(a4, b2, acc[4][2], 0, 0, 0);
        acc[4][3] = __builtin_amdgcn_mfma_f32_16x16x32_bf16(a4, b3, acc[4][3], 0, 0, 0);
        acc[5][0] = __builtin_amdgcn_mfma_f32_16x16x32_bf16(a5, b0, acc[5][0], 0, 0, 0);
        acc[5][1] = __builtin_amdgcn_mfma_f32_16x16x32_bf16(a5, b1, acc[5][1], 0, 0, 0);
        acc[5][2] = __builtin_amdgcn_mfma_f32_16x16x32_bf16(a5, b2, acc[5][2], 0, 0, 0);
        acc[5][3] = __builtin_amdgcn_mfma_f32_16x16x32_bf16(a5, b3, acc[5][3], 0, 0, 0);
        acc[6][0] = __builtin_amdgcn_mfma_f32_16x16x32_bf16(a6, b0, acc[6][0], 0, 0, 0);
        acc[6][1] = __builtin_amdgcn_mfma_f32_16x16x32_bf16(a6, b1, acc[6][1], 0, 0, 0);
        acc[6][2] = __builtin_amdgcn_mfma_f32_16x16x32_bf16(a6, b2, acc[6][2], 0, 0, 0);
        acc[6][3] = __builtin_amdgcn_mfma_f32_16x16x32_bf16(a6, b3, acc[6][3], 0, 0, 0);
        acc[7][0] = __builtin_amdgcn_mfma_f32_16x16x32_bf16(a7, b0, acc[7][0], 0, 0, 0);
        acc[7][1] = __builtin_amdgcn_mfma_f32_16x16x32_bf16(a7, b1, acc[7][1], 0, 0, 0);
        acc[7][2] = __builtin_amdgcn_mfma_f32_16x16x32_bf16(a7, b2, acc[7][2], 0, 0, 0);
        acc[7][3] = __builtin_amdgcn_mfma_f32_16x16x32_bf16(a7, b3, acc[7][3], 0, 0, 0);
        __builtin_amdgcn_s_setprio(0);
        if (gate == 0) asm volatile("s_waitcnt vmcnt(8)" ::: "memory");
        else if (gate == 1) asm volatile("s_waitcnt vmcnt(4)" ::: "memory");
        else if (gate == 2) asm volatile("s_waitcnt vmcnt(0)" ::: "memory");
        __builtin_amdgcn_s_barrier();
    };

    // prologue: stage halves 0,1,2 (12 GLDS/thread), gate half 0
    stage_half(0, 0); stage_half(0, 1);
    stage_half(1, 0); stage_half(1, 1);
    stage_half(2, 0); stage_half(2, 1);
    asm volatile("s_waitcnt vmcnt(8)" ::: "memory");
    __builtin_amdgcn_s_barrier();

    for (int H = 0; H < 124; ++H) half_body(H, true, 0);
    half_body(124, true, 0);
    half_body(125, false, 1);
    half_body(126, false, 2);
    half_body(127, false, 3);

    // epilogue: C/D layout col=lane&15, row=(lane>>4)*4+j [m89]; per-block top-2
    const int rowb = by * 256 + wm * 128;
#pragma unroll
    for (int m = 0; m < 8; ++m) {
#pragma unroll
        for (int j = 0; j < 4; ++j) {
            float v1 = acc[m][0][j];
            int i1 = bx * 256 + wn * 64 + r0;
            float v2 = -3.402823466e+38f;
#pragma unroll
            for (int n = 1; n < 4; ++n) {
                const float v = acc[m][n][j];
                const int c = bx * 256 + wn * 64 + n * 16 + r0;
                if (v > v1) { v2 = v1; v1 = v; i1 = c; }
                else { v2 = fmaxf(v2, v); }
            }
#pragma unroll
            for (int off = 1; off < 16; off <<= 1) {
                const float o1 = __shfl_xor(v1, off, 64);
                const int oi = __shfl_xor(i1, off, 64);
                const float o2 = __shfl_xor(v2, off, 64);
                if (o1 > v1 || (o1 == v1 && oi < i1)) { v2 = fmaxf(v1, o2); v1 = o1; i1 = oi; }
                else { v2 = fmaxf(v2, o1); }
            }
            const int row = rowb + m * 16 + rg * 4 + j;
            if (r0 == 0)
                cand[(size_t)row * 16 + bx * 4 + wn] = make_float4(v1, (float)i1, v2, 0.f);
            if (bx == 0 && wn == 0 && r0 < 2) s01[row * 2 + r0] = acc[m][0][j];
        }
    }
}

// ---------------- finalize pass 1: merge strips, flag close rows ----------------
__global__ void __launch_bounds__(256) finalizeA_kernel(const float4* __restrict__ cand,
                                                        const float* __restrict__ s01,
                                                        float* __restrict__ out,
                                                        int* __restrict__ wl,
                                                        int* __restrict__ wc) {
    const int row = blockIdx.x * 256 + threadIdx.x;
    const float4* c = cand + (size_t)row * 16;
    float4 c0 = c[0];
    float M = c0.x, iM = c0.y, M2 = c0.z;
#pragma unroll
    for (int k = 1; k < 16; ++k) {
        const float4 ck = c[k];
        if (ck.x > M) { M2 = fmaxf(M, ck.z); M = ck.x; iM = ck.y; }
        else { M2 = fmaxf(M2, ck.x); }
    }
    out[row] = iM;
    out[NQ + row] = (s01[row * 2 + 1] - s01[row * 2 + 0]) * 0.25f + 0.5f;
    if (M - M2 < TAU) {
        const int p = atomicAdd(wc, 1);
        wl[p] = row;
    }
}

// ---------------- pass 2: 3-term recheck, 128x256 tile, gathered A rows ----------------
__global__ void __launch_bounds__(512, 2) gemm2_kernel(const ushort_t* __restrict__ Ah,
                                                       const ushort_t* __restrict__ Al,
                                                       const ushort_t* __restrict__ Bh,
                                                       const ushort_t* __restrict__ Bl,
                                                       const int* __restrict__ wl,
                                                       const int* __restrict__ wc,
                                                       float2* __restrict__ cand2) {
    const int cnt = *wc;
    const int by = blockIdx.y;  // slot block (128 rows)
    const int bx = blockIdx.x;  // 256-col block
    if (by * 128 >= cnt) return;

    __shared__ __align__(16) ushort_t lA[2][2][128 * 32];  // [buf][hi/lo] 32 KB
    __shared__ __align__(16) ushort_t lB[2][2][256 * 32];  // 64 KB

    const int tid = threadIdx.x;
    const int lane = tid & 63;
    const int w = tid >> 6;  // 0..7
    const int wm = w >> 2;   // 0..1
    const int wn = w & 3;    // 0..3
    const int r0 = lane & 15;
    const int rg = lane >> 4;

    const int rowA = tid >> 2;
    const int gsA = (tid & 3) ^ ((rowA >> 1) & 3);
    const int arow = wl[min(by * 128 + rowA, cnt - 1)];
    const size_t offA = (size_t)arow * DK + gsA * 8;
    const int qb0 = tid, qb1 = tid + 512;
    const int rowB0 = qb0 >> 2, rowB1 = qb1 >> 2;
    const int gsB0 = (qb0 & 3) ^ ((rowB0 >> 1) & 3);
    const int gsB1 = (qb1 & 3) ^ ((rowB1 >> 1) & 3);
    const size_t offB0 = (size_t)(bx * 256 + rowB0) * DK + gsB0 * 8;
    const size_t offB1 = (size_t)(bx * 256 + rowB1) * DK + gsB1 * 8;

    f32x4 acc[4][4];
#pragma unroll
    for (int m = 0; m < 4; ++m)
#pragma unroll
        for (int n = 0; n < 4; ++n) acc[m][n] = (f32x4){0.f, 0.f, 0.f, 0.f};

    int aoff[4], boff[4];
#pragma unroll
    for (int m = 0; m < 4; ++m) {
        const int row = wm * 64 + m * 16 + r0;
        aoff[m] = row * 32 + (rg ^ ((row >> 1) & 3)) * 8;
    }
#pragma unroll
    for (int n = 0; n < 4; ++n) {
        const int col = wn * 64 + n * 16 + r0;
        boff[n] = col * 32 + (rg ^ ((col >> 1) & 3)) * 8;
    }

    auto stage = [&](int buf, int kt) {
        const size_t ko = (size_t)kt * 32;
        GLDS(Ah + offA + ko, &lA[buf][0][tid * 8]);
        GLDS(Al + offA + ko, &lA[buf][1][tid * 8]);
        GLDS(Bh + offB0 + ko, &lB[buf][0][qb0 * 8]);
        GLDS(Bl + offB0 + ko, &lB[buf][1][qb0 * 8]);
        GLDS(Bh + offB1 + ko, &lB[buf][0][qb1 * 8]);
        GLDS(Bl + offB1 + ko, &lB[buf][1][qb1 * 8]);
    };

    stage(0, 0);
    const int nK = DK / 32;  // 128
    for (int kt = 0; kt < nK; ++kt) {
        const int cur = kt & 1;
        if (kt + 1 < nK) {
            stage(cur ^ 1, kt + 1);
            asm volatile("s_waitcnt vmcnt(6)" ::: "memory");
        } else {
            asm volatile("s_waitcnt vmcnt(0)" ::: "memory");
        }
        __builtin_amdgcn_s_barrier();

        short8 bh[4], bl[4];
#pragma unroll
        for (int n = 0; n < 4; ++n) {
            bh[n] = *(const short8*)&lB[cur][0][boff[n]];
            bl[n] = *(const short8*)&lB[cur][1][boff[n]];
        }
#pragma unroll
        for (int m = 0; m < 4; ++m) {
            const short8 ah = *(const short8*)&lA[cur][0][aoff[m]];
            const short8 al = *(const short8*)&lA[cur][1][aoff[m]];
#pragma unroll
            for (int n = 0; n < 4; ++n) {
                acc[m][n] = __builtin_amdgcn_mfma_f32_16x16x32_bf16(ah, bh[n], acc[m][n], 0, 0, 0);
                acc[m][n] = __builtin_amdgcn_mfma_f32_16x16x32_bf16(ah, bl[n], acc[m][n], 0, 0, 0);
                acc[m][n] = __builtin_amdgcn_mfma_f32_16x16x32_bf16(al, bh[n], acc[m][n], 0, 0, 0);
            }
        }
        __builtin_amdgcn_s_barrier();
    }

#pragma unroll
    for (int m = 0; m < 4; ++m) {
#pragma unroll
        for (int j = 0; j < 4; ++j) {
            float best = acc[m][0][j];
            int bidx = bx * 256 + wn * 64 + r0;
#pragma unroll
            for (int n = 1; n < 4; ++n) {
                const float v = acc[m][n][j];
                const int c = bx * 256 + wn * 64 + n * 16 + r0;
                if (v > best) { best = v; bidx = c; }
            }
#pragma unroll
            for (int off = 1; off < 16; off <<= 1) {
                const float ov = __shfl_xor(best, off, 64);
                const int oi = __shfl_xor(bidx, off, 64);
                if (ov > best || (ov == best && oi < bidx)) { best = ov; bidx = oi; }
            }
            const int slotg = by * 128 + wm * 64 + m * 16 + rg * 4 + j;
            if (r0 == 0 && slotg < cnt)
                cand2[(size_t)slotg * 16 + bx * 4 + wn] = make_float2(best, (float)bidx);
        }
    }
}

// ---------------- finalize pass 2 ----------------
__global__ void __launch_bounds__(256) finalizeB_kernel(const float2* __restrict__ cand2,
                                                        const int* __restrict__ wl,
                                                        const int* __restrict__ wc,
                                                        float* __restrict__ out) {
    const int slot = blockIdx.x * 256 + threadIdx.x;
    const int cnt = *wc;
    if (slot >= cnt) return;
    const int row = wl[slot];
    const float2* c = cand2 + (size_t)slot * 16;
    float best = c[0].x;
    float bi = c[0].y;
#pragma unroll
    for (int k = 1; k < 16; ++k) {
        const float2 p = c[k];
        if (p.x > best) { best = p.x; bi = p.y; }
    }
    out[row] = bi;
}

extern "C" void kernel_launch(void* const* d_in, const int* in_sizes, int n_in,
                              void* d_out, int out_size, void* d_ws, size_t ws_size,
                              hipStream_t stream) {
    const float* hvs = (const float*)d_in[0];  // [16384,4096] f32
    const float* am  = (const float*)d_in[1];  // [1024,4096] f32
    float* out = (float*)d_out;                // [preds | eta]

    ushort_t* Bh = (ushort_t*)d_ws;                    // 8 MB
    ushort_t* Bl = Bh + (size_t)NC * DK;               // 8 MB
    ushort_t* Ah = Bl + (size_t)NC * DK;               // 128 MB
    ushort_t* Al = Ah + (size_t)NQ * DK;               // 128 MB
    float4* cand = (float4*)(Al + (size_t)NQ * DK);    // 4 MB
    float* s01 = (float*)(cand + (size_t)NQ * 16);     // 128 KB
    float2* cand2 = (float2*)(s01 + (size_t)NQ * 2);   // 2 MB
    int* wl = (int*)(cand2 + (size_t)NQ * 16);         // 64 KB
    int* wc = wl + NQ;                                 // 4 B

    hipMemsetAsync(wc, 0, sizeof(int), stream);
    norm_split_kernel<<<NC, 256, 0, stream>>>(am, Bh, Bl);
    norm_split_kernel<<<NQ, 256, 0, stream>>>(hvs, Ah, Al);
    gemm1_kernel<<<256, 512, 0, stream>>>(Ah, Bh, cand, s01);
    finalizeA_kernel<<<NQ / 256, 256, 0, stream>>>(cand, s01, out, wl, wc);
    gemm2_kernel<<<dim3(4, NQ / 128), 512, 0, stream>>>(Ah, Al, Bh, Bl, wl, wc, cand2);
    finalizeB_kernel<<<NQ / 256, 256, 0, stream>>>(cand2, wl, wc, out);
}

// Round 8
// 419.409 us; speedup vs baseline: 1.1846x; 1.1355x over previous
//
#include <hip/hip_runtime.h>
#include <hip/hip_bf16.h>

// N=16384 queries, C=1024 classes, D=4096.
// sims = l2norm(hvs) @ l2norm(am)^T ; preds = argmax ; eta = (sims[:,1]-sims[:,0])/4 + 0.5
// R8: gemm2 recheck de-latencified: compact gathered A (recheck_prep), 128x128
// blocks (8x128 grid), 4-deep LDS ring with 3 tiles in flight (vmcnt(12)).
// norm_split(hvs) writes hi only. gemm1/finalize unchanged from R7.

#define NQ 16384
#define NC 1024
#define DK 4096
#define TAU 4e-4f
#define WLMAX 8192

typedef __attribute__((ext_vector_type(8))) short short8;
typedef __attribute__((ext_vector_type(4))) float f32x4;
typedef unsigned short ushort_t;

__device__ __forceinline__ unsigned short bf16_rne(float x) {
    unsigned int u = __float_as_uint(x);
    u += 0x7FFFu + ((u >> 16) & 1u);
    return (unsigned short)(u >> 16);
}
__device__ __forceinline__ float bf16_f32(unsigned short h) {
    return __uint_as_float(((unsigned int)h) << 16);
}

#define GLDS(g, l)                                                                       \
    __builtin_amdgcn_global_load_lds((const __attribute__((address_space(1))) void*)(g), \
                                     (__attribute__((address_space(3))) void*)(l), 16, 0, 0)

// ---------------- fused row-norm + normalize + bf16 hi(/lo) split ----------------
__global__ void __launch_bounds__(256) norm_split_kernel(const float* __restrict__ x,
                                                         ushort_t* __restrict__ hi,
                                                         ushort_t* __restrict__ lo,
                                                         int write_lo) {
    const int row = blockIdx.x;
    const int tid = threadIdx.x;
    const float4* x4 = (const float4*)(x + (size_t)row * DK);

    float4 v[4];
    float ss = 0.f;
#pragma unroll
    for (int i = 0; i < 4; ++i) {
        v[i] = x4[tid * 4 + i];
        ss += v[i].x * v[i].x + v[i].y * v[i].y + v[i].z * v[i].z + v[i].w * v[i].w;
    }
#pragma unroll
    for (int off = 32; off; off >>= 1) ss += __shfl_xor(ss, off, 64);
    __shared__ float wsum[4];
    const int lane = tid & 63, w = tid >> 6;
    if (lane == 0) wsum[w] = ss;
    __syncthreads();
    const float tot = wsum[0] + wsum[1] + wsum[2] + wsum[3];
    const float r = 1.0f / fmaxf(sqrtf(tot), 1e-8f);

    ushort_t hbuf[16], lbuf[16];
#pragma unroll
    for (int i = 0; i < 4; ++i) {
        const float xs[4] = {v[i].x * r, v[i].y * r, v[i].z * r, v[i].w * r};
#pragma unroll
        for (int j = 0; j < 4; ++j) {
            const unsigned short h = bf16_rne(xs[j]);
            hbuf[i * 4 + j] = h;
            lbuf[i * 4 + j] = bf16_rne(xs[j] - bf16_f32(h));
        }
    }
    ushort_t* hp = hi + (size_t)row * DK + tid * 16;
    *(short8*)hp = *(short8*)hbuf;
    *(short8*)(hp + 8) = *(short8*)(hbuf + 8);
    if (write_lo) {
        ushort_t* lp = lo + (size_t)row * DK + tid * 16;
        *(short8*)lp = *(short8*)lbuf;
        *(short8*)(lp + 8) = *(short8*)(lbuf + 8);
    }
}

// ---------------- pass 1: 1-term bf16 GEMM, half-tile ring, fused top-2 ----------------
// (unchanged from R7)
__global__ void __launch_bounds__(512, 2) gemm1_kernel(const ushort_t* __restrict__ Ah,
                                                       const ushort_t* __restrict__ Bh,
                                                       float4* __restrict__ cand,
                                                       float* __restrict__ s01) {
    __shared__ __align__(16) ushort_t lA[4][256 * 32];  // 64 KB
    __shared__ __align__(16) ushort_t lB[4][256 * 32];  // 64 KB

    const int tid = threadIdx.x;
    const int lane = tid & 63;
    const int w = tid >> 6;
    const int wm = w >> 2;
    const int wn = w & 3;

    const int id = blockIdx.x;
    const int xcd = id & 7;
    const int slot = id >> 3;
    const int by = xcd * 8 + (slot >> 2);
    const int bx = slot & 3;

    int sq[2];
    size_t offA[2], offB[2];
#pragma unroll
    for (int i = 0; i < 2; ++i) {
        const int q = tid + i * 512;
        sq[i] = q;
        const int row = q >> 2;
        const int gs = (q & 3) ^ ((row >> 1) & 3);
        offA[i] = (size_t)(by * 256 + row) * DK + gs * 8;
        offB[i] = (size_t)(bx * 256 + row) * DK + gs * 8;
    }

    f32x4 acc[8][4];
#pragma unroll
    for (int m = 0; m < 8; ++m)
#pragma unroll
        for (int n = 0; n < 4; ++n) acc[m][n] = (f32x4){0.f, 0.f, 0.f, 0.f};

    const int r0 = lane & 15;
    const int rg = lane >> 4;

    int aoff[8], boff[4];
#pragma unroll
    for (int m = 0; m < 8; ++m) {
        const int row = wm * 128 + m * 16 + r0;
        aoff[m] = row * 32 + (rg ^ ((row >> 1) & 3)) * 8;
    }
#pragma unroll
    for (int n = 0; n < 4; ++n) {
        const int col = wn * 64 + n * 16 + r0;
        boff[n] = col * 32 + (rg ^ ((col >> 1) & 3)) * 8;
    }

    auto stage_half = [&](int H, int i) {
        const int buf = H & 3;
        const size_t ko = (size_t)H * 32;
        GLDS(Ah + offA[i] + ko, &lA[buf][sq[i] * 8]);
        GLDS(Bh + offB[i] + ko, &lB[buf][sq[i] * 8]);
    };

    auto half_body = [&](int H, bool st, int gate) {
        const int buf = H & 3;
        const ushort_t* __restrict__ pA = &lA[buf][0];
        const ushort_t* __restrict__ pB = &lB[buf][0];
        short8 b0 = *(const short8*)&pB[boff[0]];
        short8 b1 = *(const short8*)&pB[boff[1]];
        short8 b2 = *(const short8*)&pB[boff[2]];
        short8 b3 = *(const short8*)&pB[boff[3]];
        short8 a0 = *(const short8*)&pA[aoff[0]];
        short8 a1 = *(const short8*)&pA[aoff[1]];
        short8 a2 = *(const short8*)&pA[aoff[2]];
        short8 a3 = *(const short8*)&pA[aoff[3]];
        if (st) stage_half(H + 3, 0);
        __builtin_amdgcn_s_barrier();
        asm volatile("s_waitcnt lgkmcnt(0)" ::: "memory");
        __builtin_amdgcn_s_setprio(1);
        acc[0][0] = __builtin_amdgcn_mfma_f32_16x16x32_bf16(a0, b0, acc[0][0], 0, 0, 0);
        acc[0][1] = __builtin_amdgcn_mfma_f32_16x16x32_bf16(a0, b1, acc[0][1], 0, 0, 0);
        acc[0][2] = __builtin_amdgcn_mfma_f32_16x16x32_bf16(a0, b2, acc[0][2], 0, 0, 0);
        acc[0][3] = __builtin_amdgcn_mfma_f32_16x16x32_bf16(a0, b3, acc[0][3], 0, 0, 0);
        acc[1][0] = __builtin_amdgcn_mfma_f32_16x16x32_bf16(a1, b0, acc[1][0], 0, 0, 0);
        acc[1][1] = __builtin_amdgcn_mfma_f32_16x16x32_bf16(a1, b1, acc[1][1], 0, 0, 0);
        acc[1][2] = __builtin_amdgcn_mfma_f32_16x16x32_bf16(a1, b2, acc[1][2], 0, 0, 0);
        acc[1][3] = __builtin_amdgcn_mfma_f32_16x16x32_bf16(a1, b3, acc[1][3], 0, 0, 0);
        acc[2][0] = __builtin_amdgcn_mfma_f32_16x16x32_bf16(a2, b0, acc[2][0], 0, 0, 0);
        acc[2][1] = __builtin_amdgcn_mfma_f32_16x16x32_bf16(a2, b1, acc[2][1], 0, 0, 0);
        acc[2][2] = __builtin_amdgcn_mfma_f32_16x16x32_bf16(a2, b2, acc[2][2], 0, 0, 0);
        acc[2][3] = __builtin_amdgcn_mfma_f32_16x16x32_bf16(a2, b3, acc[2][3], 0, 0, 0);
        acc[3][0] = __builtin_amdgcn_mfma_f32_16x16x32_bf16(a3, b0, acc[3][0], 0, 0, 0);
        acc[3][1] = __builtin_amdgcn_mfma_f32_16x16x32_bf16(a3, b1, acc[3][1], 0, 0, 0);
        acc[3][2] = __builtin_amdgcn_mfma_f32_16x16x32_bf16(a3, b2, acc[3][2], 0, 0, 0);
        acc[3][3] = __builtin_amdgcn_mfma_f32_16x16x32_bf16(a3, b3, acc[3][3], 0, 0, 0);
        __builtin_amdgcn_s_setprio(0);
        __builtin_amdgcn_s_barrier();
        short8 a4 = *(const short8*)&pA[aoff[4]];
        short8 a5 = *(const short8*)&pA[aoff[5]];
        short8 a6 = *(const short8*)&pA[aoff[6]];
        short8 a7 = *(const short8*)&pA[aoff[7]];
        if (st) stage_half(H + 3, 1);
        __builtin_amdgcn_s_barrier();
        asm volatile("s_waitcnt lgkmcnt(0)" ::: "memory");
        __builtin_amdgcn_s_setprio(1);
        acc[4][0] = __builtin_amdgcn_mfma_f32_16x16x32_bf16(a4, b0, acc[4][0], 0, 0, 0);
        acc[4][1] = __builtin_amdgcn_mfma_f32_16x16x32_bf16(a4, b1, acc[4][1], 0, 0, 0);
        acc[4][2] = __builtin_amdgcn_mfma_f32_16x16x32_bf16(a4, b2, acc[4][2], 0, 0, 0);
        acc[4][3] = __builtin_amdgcn_mfma_f32_16x16x32_bf16(a4, b3, acc[4][3], 0, 0, 0);
        acc[5][0] = __builtin_amdgcn_mfma_f32_16x16x32_bf16(a5, b0, acc[5][0], 0, 0, 0);
        acc[5][1] = __builtin_amdgcn_mfma_f32_16x16x32_bf16(a5, b1, acc[5][1], 0, 0, 0);
        acc[5][2] = __builtin_amdgcn_mfma_f32_16x16x32_bf16(a5, b2, acc[5][2], 0, 0, 0);
        acc[5][3] = __builtin_amdgcn_mfma_f32_16x16x32_bf16(a5, b3, acc[5][3], 0, 0, 0);
        acc[6][0] = __builtin_amdgcn_mfma_f32_16x16x32_bf16(a6, b0, acc[6][0], 0, 0, 0);
        acc[6][1] = __builtin_amdgcn_mfma_f32_16x16x32_bf16(a6, b1, acc[6][1], 0, 0, 0);
        acc[6][2] = __builtin_amdgcn_mfma_f32_16x16x32_bf16(a6, b2, acc[6][2], 0, 0, 0);
        acc[6][3] = __builtin_amdgcn_mfma_f32_16x16x32_bf16(a6, b3, acc[6][3], 0, 0, 0);
        acc[7][0] = __builtin_amdgcn_mfma_f32_16x16x32_bf16(a7, b0, acc[7][0], 0, 0, 0);
        acc[7][1] = __builtin_amdgcn_mfma_f32_16x16x32_bf16(a7, b1, acc[7][1], 0, 0, 0);
        acc[7][2] = __builtin_amdgcn_mfma_f32_16x16x32_bf16(a7, b2, acc[7][2], 0, 0, 0);
        acc[7][3] = __builtin_amdgcn_mfma_f32_16x16x32_bf16(a7, b3, acc[7][3], 0, 0, 0);
        __builtin_amdgcn_s_setprio(0);
        if (gate == 0) asm volatile("s_waitcnt vmcnt(8)" ::: "memory");
        else if (gate == 1) asm volatile("s_waitcnt vmcnt(4)" ::: "memory");
        else if (gate == 2) asm volatile("s_waitcnt vmcnt(0)" ::: "memory");
        __builtin_amdgcn_s_barrier();
    };

    stage_half(0, 0); stage_half(0, 1);
    stage_half(1, 0); stage_half(1, 1);
    stage_half(2, 0); stage_half(2, 1);
    asm volatile("s_waitcnt vmcnt(8)" ::: "memory");
    __builtin_amdgcn_s_barrier();

    for (int H = 0; H < 124; ++H) half_body(H, true, 0);
    half_body(124, true, 0);
    half_body(125, false, 1);
    half_body(126, false, 2);
    half_body(127, false, 3);

    const int rowb = by * 256 + wm * 128;
#pragma unroll
    for (int m = 0; m < 8; ++m) {
#pragma unroll
        for (int j = 0; j < 4; ++j) {
            float v1 = acc[m][0][j];
            int i1 = bx * 256 + wn * 64 + r0;
            float v2 = -3.402823466e+38f;
#pragma unroll
            for (int n = 1; n < 4; ++n) {
                const float v = acc[m][n][j];
                const int c = bx * 256 + wn * 64 + n * 16 + r0;
                if (v > v1) { v2 = v1; v1 = v; i1 = c; }
                else { v2 = fmaxf(v2, v); }
            }
#pragma unroll
            for (int off = 1; off < 16; off <<= 1) {
                const float o1 = __shfl_xor(v1, off, 64);
                const int oi = __shfl_xor(i1, off, 64);
                const float o2 = __shfl_xor(v2, off, 64);
                if (o1 > v1 || (o1 == v1 && oi < i1)) { v2 = fmaxf(v1, o2); v1 = o1; i1 = oi; }
                else { v2 = fmaxf(v2, o1); }
            }
            const int row = rowb + m * 16 + rg * 4 + j;
            if (r0 == 0)
                cand[(size_t)row * 16 + bx * 4 + wn] = make_float4(v1, (float)i1, v2, 0.f);
            if (bx == 0 && wn == 0 && r0 < 2) s01[row * 2 + r0] = acc[m][0][j];
        }
    }
}

// ---------------- finalize pass 1: merge strips, flag close rows ----------------
__global__ void __launch_bounds__(256) finalizeA_kernel(const float4* __restrict__ cand,
                                                        const float* __restrict__ s01,
                                                        float* __restrict__ out,
                                                        int* __restrict__ wl,
                                                        int* __restrict__ wc) {
    const int row = blockIdx.x * 256 + threadIdx.x;
    const float4* c = cand + (size_t)row * 16;
    float4 c0 = c[0];
    float M = c0.x, iM = c0.y, M2 = c0.z;
#pragma unroll
    for (int k = 1; k < 16; ++k) {
        const float4 ck = c[k];
        if (ck.x > M) { M2 = fmaxf(M, ck.z); M = ck.x; iM = ck.y; }
        else { M2 = fmaxf(M2, ck.x); }
    }
    out[row] = iM;
    out[NQ + row] = (s01[row * 2 + 1] - s01[row * 2 + 0]) * 0.25f + 0.5f;
    if (M - M2 < TAU) {
        const int p = atomicAdd(wc, 1);
        if (p < WLMAX) wl[p] = row;
    }
}

// ---------------- recheck prep: gather flagged rows, normalize + hi/lo split ----------------
__global__ void __launch_bounds__(256) recheck_prep_kernel(const float* __restrict__ hvs,
                                                           const int* __restrict__ wl,
                                                           const int* __restrict__ wc,
                                                           ushort_t* __restrict__ A2h,
                                                           ushort_t* __restrict__ A2l) {
    const int cnt = min(*wc, WLMAX);
    const int s = blockIdx.x;
    if (s >= cnt) return;
    const int row = wl[s];
    const int tid = threadIdx.x;
    const float4* x4 = (const float4*)(hvs + (size_t)row * DK);

    float4 v[4];
    float ss = 0.f;
#pragma unroll
    for (int i = 0; i < 4; ++i) {
        v[i] = x4[tid * 4 + i];
        ss += v[i].x * v[i].x + v[i].y * v[i].y + v[i].z * v[i].z + v[i].w * v[i].w;
    }
#pragma unroll
    for (int off = 32; off; off >>= 1) ss += __shfl_xor(ss, off, 64);
    __shared__ float wsum[4];
    const int lane = tid & 63, w = tid >> 6;
    if (lane == 0) wsum[w] = ss;
    __syncthreads();
    const float tot = wsum[0] + wsum[1] + wsum[2] + wsum[3];
    const float r = 1.0f / fmaxf(sqrtf(tot), 1e-8f);

    ushort_t hbuf[16], lbuf[16];
#pragma unroll
    for (int i = 0; i < 4; ++i) {
        const float xs[4] = {v[i].x * r, v[i].y * r, v[i].z * r, v[i].w * r};
#pragma unroll
        for (int j = 0; j < 4; ++j) {
            const unsigned short h = bf16_rne(xs[j]);
            hbuf[i * 4 + j] = h;
            lbuf[i * 4 + j] = bf16_rne(xs[j] - bf16_f32(h));
        }
    }
    ushort_t* hp = A2h + (size_t)s * DK + tid * 16;
    ushort_t* lp = A2l + (size_t)s * DK + tid * 16;
    *(short8*)hp = *(short8*)hbuf;
    *(short8*)(hp + 8) = *(short8*)(hbuf + 8);
    *(short8*)lp = *(short8*)lbuf;
    *(short8*)(lp + 8) = *(short8*)(lbuf + 8);
}

// ---------------- pass 2: 3-term recheck, 128x128 blocks, 4-deep ring ----------------
// 8 waves (2M x 4N: 64-row x 32-col strips), LDS 128 KB, 3 tiles in flight.
// Per-acc arithmetic order identical to the proven R3 3-term path.
__global__ void __launch_bounds__(512, 2) gemm2_kernel(const ushort_t* __restrict__ A2h,
                                                       const ushort_t* __restrict__ A2l,
                                                       const ushort_t* __restrict__ Bh,
                                                       const ushort_t* __restrict__ Bl,
                                                       const int* __restrict__ wc,
                                                       float2* __restrict__ cand2) {
    const int cnt = min(*wc, WLMAX);
    const int by = blockIdx.y;  // 128-slot block
    const int bx = blockIdx.x;  // 128-col block (0..7)
    if (by * 128 >= cnt) return;

    __shared__ __align__(16) ushort_t lA[4][2][128 * 32];  // 64 KB
    __shared__ __align__(16) ushort_t lB[4][2][128 * 32];  // 64 KB

    const int tid = threadIdx.x;
    const int lane = tid & 63;
    const int w = tid >> 6;  // 0..7
    const int wm = w >> 2;   // 0..1 (64-row strip)
    const int wn = w & 3;    // 0..3 (32-col strip)
    const int r0 = lane & 15;
    const int rg = lane >> 4;

    // staging: A tile 128 slots x 4 slots16B = 512 chunks, 1/thread (hi+lo);
    //          B tile 128 cols x 4 = 512 chunks, 1/thread (hi+lo). 4 GLDS/thread/iter.
    const int srow = tid >> 2;
    const int gs = (tid & 3) ^ ((srow >> 1) & 3);
    const size_t offA = (size_t)(by * 128 + srow) * DK + gs * 8;
    const size_t offB = (size_t)(bx * 128 + srow) * DK + gs * 8;

    f32x4 acc[4][2];
#pragma unroll
    for (int m = 0; m < 4; ++m)
#pragma unroll
        for (int n = 0; n < 2; ++n) acc[m][n] = (f32x4){0.f, 0.f, 0.f, 0.f};

    int aoff[4], boff[2];
#pragma unroll
    for (int m = 0; m < 4; ++m) {
        const int row = wm * 64 + m * 16 + r0;
        aoff[m] = row * 32 + (rg ^ ((row >> 1) & 3)) * 8;
    }
#pragma unroll
    for (int n = 0; n < 2; ++n) {
        const int col = wn * 32 + n * 16 + r0;
        boff[n] = col * 32 + (rg ^ ((col >> 1) & 3)) * 8;
    }

    auto stage = [&](int kt) {
        const int buf = kt & 3;
        const size_t ko = (size_t)kt * 32;
        GLDS(A2h + offA + ko, &lA[buf][0][tid * 8]);
        GLDS(A2l + offA + ko, &lA[buf][1][tid * 8]);
        GLDS(Bh + offB + ko, &lB[buf][0][tid * 8]);
        GLDS(Bl + offB + ko, &lB[buf][1][tid * 8]);
    };

    stage(0); stage(1); stage(2);  // 12 loads/thread in flight
    const int nK = DK / 32;        // 128
    for (int kt = 0; kt < nK; ++kt) {
        const int buf = kt & 3;
        if (kt + 3 < nK) {
            stage(kt + 3);                                     // 16 in flight
            asm volatile("s_waitcnt vmcnt(12)" ::: "memory");  // tile kt done
        } else if (kt + 3 == nK) {
            asm volatile("s_waitcnt vmcnt(8)" ::: "memory");
        } else if (kt + 2 == nK) {
            asm volatile("s_waitcnt vmcnt(4)" ::: "memory");
        } else {
            asm volatile("s_waitcnt vmcnt(0)" ::: "memory");
        }
        __builtin_amdgcn_s_barrier();

        short8 bh[2], bl[2];
#pragma unroll
        for (int n = 0; n < 2; ++n) {
            bh[n] = *(const short8*)&lB[buf][0][boff[n]];
            bl[n] = *(const short8*)&lB[buf][1][boff[n]];
        }
#pragma unroll
        for (int m = 0; m < 4; ++m) {
            const short8 ah = *(const short8*)&lA[buf][0][aoff[m]];
            const short8 al = *(const short8*)&lA[buf][1][aoff[m]];
#pragma unroll
            for (int n = 0; n < 2; ++n) {
                acc[m][n] = __builtin_amdgcn_mfma_f32_16x16x32_bf16(ah, bh[n], acc[m][n], 0, 0, 0);
                acc[m][n] = __builtin_amdgcn_mfma_f32_16x16x32_bf16(ah, bl[n], acc[m][n], 0, 0, 0);
                acc[m][n] = __builtin_amdgcn_mfma_f32_16x16x32_bf16(al, bh[n], acc[m][n], 0, 0, 0);
            }
        }
        __builtin_amdgcn_s_barrier();
    }

    // epilogue: per (m,j) slot-row, argmax over wave's 32 cols -> cand2[slot][bx*4+wn]
#pragma unroll
    for (int m = 0; m < 4; ++m) {
#pragma unroll
        for (int j = 0; j < 4; ++j) {
            float best = acc[m][0][j];
            int bidx = bx * 128 + wn * 32 + r0;
            {
                const float v = acc[m][1][j];
                const int c = bx * 128 + wn * 32 + 16 + r0;
                if (v > best) { best = v; bidx = c; }
            }
#pragma unroll
            for (int off = 1; off < 16; off <<= 1) {
                const float ov = __shfl_xor(best, off, 64);
                const int oi = __shfl_xor(bidx, off, 64);
                if (ov > best || (ov == best && oi < bidx)) { best = ov; bidx = oi; }
            }
            const int slotg = by * 128 + wm * 64 + m * 16 + rg * 4 + j;
            if (r0 == 0 && slotg < cnt)
                cand2[(size_t)slotg * 32 + bx * 4 + wn] = make_float2(best, (float)bidx);
        }
    }
}

// ---------------- finalize pass 2 ----------------
__global__ void __launch_bounds__(256) finalizeB_kernel(const float2* __restrict__ cand2,
                                                        const int* __restrict__ wl,
                                                        const int* __restrict__ wc,
                                                        float* __restrict__ out) {
    const int slot = blockIdx.x * 256 + threadIdx.x;
    const int cnt = min(*wc, WLMAX);
    if (slot >= cnt) return;
    const int row = wl[slot];
    const float2* c = cand2 + (size_t)slot * 32;
    float best = c[0].x;
    float bi = c[0].y;
#pragma unroll
    for (int k = 1; k < 32; ++k) {
        const float2 p = c[k];
        if (p.x > best) { best = p.x; bi = p.y; }  // ascending cols: strict > keeps first
    }
    out[row] = bi;
}

extern "C" void kernel_launch(void* const* d_in, const int* in_sizes, int n_in,
                              void* d_out, int out_size, void* d_ws, size_t ws_size,
                              hipStream_t stream) {
    const float* hvs = (const float*)d_in[0];  // [16384,4096] f32
    const float* am  = (const float*)d_in[1];  // [1024,4096] f32
    float* out = (float*)d_out;                // [preds | eta]

    ushort_t* Bh = (ushort_t*)d_ws;                    // 8 MB
    ushort_t* Bl = Bh + (size_t)NC * DK;               // 8 MB
    ushort_t* Ah = Bl + (size_t)NC * DK;               // 128 MB
    ushort_t* A2h = Ah + (size_t)NQ * DK;              // 64 MB (WLMAX rows)
    ushort_t* A2l = A2h + (size_t)WLMAX * DK;          // 64 MB
    float4* cand = (float4*)(A2l + (size_t)WLMAX * DK);  // 4 MB
    float* s01 = (float*)(cand + (size_t)NQ * 16);       // 128 KB
    float2* cand2 = (float2*)(s01 + (size_t)NQ * 2);     // 4 MB (WLMAX x 32)
    int* wl = (int*)(cand2 + (size_t)WLMAX * 32);        // 32 KB
    int* wc = wl + WLMAX;                                // 4 B

    hipMemsetAsync(wc, 0, sizeof(int), stream);
    norm_split_kernel<<<NC, 256, 0, stream>>>(am, Bh, Bl, 1);
    norm_split_kernel<<<NQ, 256, 0, stream>>>(hvs, Ah, nullptr, 0);
    gemm1_kernel<<<256, 512, 0, stream>>>(Ah, Bh, cand, s01);
    finalizeA_kernel<<<NQ / 256, 256, 0, stream>>>(cand, s01, out, wl, wc);
    recheck_prep_kernel<<<WLMAX, 256, 0, stream>>>(hvs, wl, wc, A2h, A2l);
    gemm2_kernel<<<dim3(8, WLMAX / 128), 512, 0, stream>>>(A2h, A2l, Bh, Bl, wc, cand2);
    finalizeB_kernel<<<WLMAX / 256, 256, 0, stream>>>(cand2, wl, wc, out);
}